// Round 1
// baseline (1348.872 us; speedup 1.0000x reference)
//
#include <hip/hip_runtime.h>
#include <hip/hip_bf16.h>
#include <stdint.h>

typedef __bf16 bf16_t;
typedef __bf16 bf16x8 __attribute__((ext_vector_type(8)));
typedef __bf16 bf16x4 __attribute__((ext_vector_type(4)));
typedef float f32x4 __attribute__((ext_vector_type(4)));

// ---------------------------------------------------------------------------
// transpose-convert: out[n][k] = (bf16) in[k][n];  in is K x N f32 row-major
// ---------------------------------------------------------------------------
__global__ void transp_kernel(const float* __restrict__ in, bf16_t* __restrict__ out,
                              int K, int N) {
  __shared__ float tile[32][33];
  int k0 = blockIdx.x * 32, n0 = blockIdx.y * 32;
  int tx = threadIdx.x, ty = threadIdx.y;
#pragma unroll
  for (int i = 0; i < 4; i++)
    tile[ty + 8 * i][tx] = in[(size_t)(k0 + ty + 8 * i) * N + n0 + tx];
  __syncthreads();
#pragma unroll
  for (int i = 0; i < 4; i++)
    out[(size_t)(n0 + ty + 8 * i) * K + k0 + tx] = (bf16_t)tile[tx][ty + 8 * i];
}

// ---------------------------------------------------------------------------
// FeatureNorm over the SEQUENCE dim (axis=1), per (b, d) column of (B,1024,D).
// MODE 1: + pos_enc then swish (pre-QKV).  MODE 2: plain.  MODE 3: swish.
// Output bf16.
// ---------------------------------------------------------------------------
template <int MODE>
__global__ __launch_bounds__(256) void norm_kernel(
    const float* __restrict__ in, const float* __restrict__ gamma,
    const float* __restrict__ beta, const float* __restrict__ pos,
    bf16_t* __restrict__ out, int D) {
  const int nd = D >> 7;
  const int b = blockIdx.x / nd;
  const int dc = blockIdx.x % nd;
  const int t = threadIdx.x;
  const int d = (dc << 7) + (t & 127);
  const int half = t >> 7;
  const float* base = in + (size_t)b * 1024 * D + d;
  float sum = 0.f, sq = 0.f;
  for (int n = half; n < 1024; n += 2) {
    float v = base[(size_t)n * D];
    sum += v;
    sq += v * v;
  }
  __shared__ float r0[256], r1[256];
  __shared__ float ms[128], rs[128];
  r0[t] = sum;
  r1[t] = sq;
  __syncthreads();
  if (t < 128) {
    float s = r0[t] + r0[t + 128];
    float q = r1[t] + r1[t + 128];
    float mean = s * (1.f / 1024.f);
    float var = q * (1.f / 1024.f) - mean * mean;
    ms[t] = mean;
    rs[t] = rsqrtf(var + 1e-5f);
  }
  __syncthreads();
  const float mean = ms[t & 127], rinv = rs[t & 127];
  const float g = gamma[d], be = beta[d];
  bf16_t* ob = out + (size_t)b * 1024 * D + d;
  for (int n = half; n < 1024; n += 2) {
    float v = base[(size_t)n * D];
    float hh = g * (v - mean) * rinv + be;
    if (MODE == 1) hh += pos[(size_t)n * D + d];
    if (MODE == 1 || MODE == 3) hh = hh / (1.f + __expf(-hh));
    ob[(size_t)n * D] = (bf16_t)hh;
  }
}

// ---------------------------------------------------------------------------
// bf16 GEMM, m97-style: 128x128 tile, BK=64, 4 waves (each 64x64),
// global_load_lds width=16, XOR-swizzled LDS ((row&7) on 16B chunks).
// A: M x K row-major bf16.  Bt: N x K row-major bf16 (i.e. B transposed).
// EPI_QKV : out bf16; cols<1024 -> qk buffer as-is (+bias);
//           cols>=1024 -> V written TRANSPOSED into (B,H,512,1024) (+bias).
// EPI_F32 : out f32 = acc + bias.
// EPI_F32RES: out f32 = acc + bias + res.
// ---------------------------------------------------------------------------
enum { EPI_QKV = 0, EPI_F32 = 1, EPI_F32RES = 2 };

template <int EPI>
__global__ void __launch_bounds__(256, 2) gemm_bf16(
    const bf16_t* __restrict__ A, const bf16_t* __restrict__ Bt,
    const float* __restrict__ bias, const float* __restrict__ res,
    void* __restrict__ out0, bf16_t* __restrict__ out1,
    int M, int N, int K) {
  __shared__ bf16_t smem[2 * 128 * 64];
  bf16_t* sA = smem;
  bf16_t* sB = smem + 128 * 64;
  const int mt = M >> 7;
  const int bm = blockIdx.x % mt;
  const int bn = blockIdx.x / mt;
  const int t = threadIdx.x;
  const int w = t >> 6, l = t & 63;
  const int wm = w >> 1, wn = w & 1;
  const int lrow = l >> 3;
  const int lcol = (l & 7) ^ lrow;  // pre-swizzled global 16B-chunk index

  f32x4 acc[4][4];
  const f32x4 z4 = {0.f, 0.f, 0.f, 0.f};
#pragma unroll
  for (int m = 0; m < 4; m++)
#pragma unroll
    for (int n = 0; n < 4; n++) acc[m][n] = z4;

  const bf16_t* Asrc = A + (size_t)(bm * 128 + w * 32 + lrow) * K + lcol * 8;
  const bf16_t* Bsrc = Bt + (size_t)(bn * 128 + w * 32 + lrow) * K + lcol * 8;

  for (int kk = 0; kk < K; kk += 64) {
#pragma unroll
    for (int i = 0; i < 4; i++) {
      __builtin_amdgcn_global_load_lds(
          (const __attribute__((address_space(1))) void*)(const void*)(Asrc + (size_t)i * 8 * K + kk),
          (__attribute__((address_space(3))) void*)(void*)((char*)sA + (w * 4 + i) * 1024),
          16, 0, 0);
      __builtin_amdgcn_global_load_lds(
          (const __attribute__((address_space(1))) void*)(const void*)(Bsrc + (size_t)i * 8 * K + kk),
          (__attribute__((address_space(3))) void*)(void*)((char*)sB + (w * 4 + i) * 1024),
          16, 0, 0);
    }
    __syncthreads();
#pragma unroll
    for (int ks = 0; ks < 2; ks++) {
      bf16x8 af[4], bfr[4];
      const int lc = ks * 4 + (l >> 4);
#pragma unroll
      for (int m = 0; m < 4; m++) {
        int row = wm * 64 + m * 16 + (l & 15);
        af[m] = *(const bf16x8*)((const char*)sA + row * 128 + ((lc ^ (row & 7)) << 4));
      }
#pragma unroll
      for (int n = 0; n < 4; n++) {
        int row = wn * 64 + n * 16 + (l & 15);
        bfr[n] = *(const bf16x8*)((const char*)sB + row * 128 + ((lc ^ (row & 7)) << 4));
      }
#pragma unroll
      for (int m = 0; m < 4; m++)
#pragma unroll
        for (int n = 0; n < 4; n++)
          acc[m][n] = __builtin_amdgcn_mfma_f32_16x16x32_bf16(af[m], bfr[n], acc[m][n], 0, 0, 0);
    }
    __syncthreads();
  }

  const int rowbase = bm * 128 + wm * 64 + ((l >> 4) << 2);
  const int colbase = bn * 128 + wn * 64 + (l & 15);
#pragma unroll
  for (int m = 0; m < 4; m++) {
#pragma unroll
    for (int n = 0; n < 4; n++) {
      int row = rowbase + m * 16;
      int col = colbase + n * 16;
      float bc = bias[col];
      if (EPI == EPI_QKV) {
        if (col < 1024) {
          bf16_t* qkb = (bf16_t*)out0;
#pragma unroll
          for (int r = 0; r < 4; r++)
            qkb[(size_t)(row + r) * 1024 + col] = (bf16_t)(acc[m][n][r] + bc);
        } else {
          int c2 = col - 1024;
          int hh = c2 >> 9, vc = c2 & 511;
          int bidx = row >> 10, nidx = row & 1023;
          bf16x4 pk;
#pragma unroll
          for (int r = 0; r < 4; r++) pk[r] = (bf16_t)(acc[m][n][r] + bc);
          *(bf16x4*)(out1 + ((size_t)((bidx << 3) + hh) * 512 + vc) * 1024 + nidx) = pk;
        }
      } else {
        float* o = (float*)out0;
#pragma unroll
        for (int r = 0; r < 4; r++) {
          float v = acc[m][n][r] + bc;
          if (EPI == EPI_F32RES) v += res[(size_t)(row + r) * N + col];
          o[(size_t)(row + r) * N + col] = v;
        }
      }
    }
  }
}

// ---------------------------------------------------------------------------
// per-(b,h,n) |q|^2 and |k|^2 over the 64-dim head (from bf16 q/k, f32 accum)
// ---------------------------------------------------------------------------
__global__ void q2k2_kernel(const bf16_t* __restrict__ qk, float* __restrict__ q2,
                            float* __restrict__ k2) {
  int tid = blockIdx.x * 256 + threadIdx.x;  // (b*8+h)*1024 + n
  int b = tid >> 13;
  int h = (tid >> 10) & 7;
  int n = tid & 1023;
  const bf16_t* row = qk + (size_t)((b << 10) + n) * 1024 + (h << 6);
  float sq = 0.f, sk = 0.f;
#pragma unroll
  for (int i = 0; i < 8; i++) {
    bf16x8 vq = *(const bf16x8*)(row + i * 8);
    bf16x8 vk = *(const bf16x8*)(row + 512 + i * 8);
#pragma unroll
    for (int j = 0; j < 8; j++) {
      float fq = (float)vq[j];
      sq += fq * fq;
      float fk = (float)vk[j];
      sk += fk * fk;
    }
  }
  q2[tid] = sq;
  k2[tid] = sk;
}

// ---------------------------------------------------------------------------
// RBF attention: per block (b,h, 64 q-rows).  4 waves.
// S^T = mfma(K,Q) so the P write to LDS is 4-contiguous-j b64 stores.
// score = exp(-max(q2+k2-2qk,0)/scale^2); O = score @ V via LDS-S (A-op) and
// global V^T (B-op, contiguous in kv index).  acc 64x512 f32 per block.
// ---------------------------------------------------------------------------
__global__ void __launch_bounds__(256, 2) attn_kernel(
    const bf16_t* __restrict__ qk, const bf16_t* __restrict__ vt,
    const float* __restrict__ q2, const float* __restrict__ k2,
    const float* __restrict__ scale_p, bf16_t* __restrict__ attn_out) {
  __shared__ bf16_t s_lds[64 * 64];
  const int blk = blockIdx.x;
  const int mtile = blk & 15;
  const int bh = blk >> 4;
  const int b = bh >> 3, h = bh & 7;
  const int t = threadIdx.x, w = t >> 6, l = t & 63;
  const float sc = scale_p[0];
  const float minus_inv = -1.f / (sc * sc);

  const bf16_t* qbase = qk + ((size_t)((b << 10) + (mtile << 6))) * 1024 + (h << 6);
  bf16x8 qf[4][2];
#pragma unroll
  for (int it = 0; it < 4; it++)
#pragma unroll
    for (int kc = 0; kc < 2; kc++)
      qf[it][kc] = *(const bf16x8*)(qbase + (size_t)(it * 16 + (l & 15)) * 1024 +
                                    kc * 32 + ((l >> 4) << 3));
  float q2r[4];
  const float* q2base = q2 + (bh << 10) + (mtile << 6);
#pragma unroll
  for (int it = 0; it < 4; it++) q2r[it] = q2base[it * 16 + (l & 15)];

  f32x4 acc[4][8];
  const f32x4 z4 = {0.f, 0.f, 0.f, 0.f};
#pragma unroll
  for (int m = 0; m < 4; m++)
#pragma unroll
    for (int nn = 0; nn < 8; nn++) acc[m][nn] = z4;

  const bf16_t* kbase = qk + ((size_t)(b << 10)) * 1024 + 512 + (h << 6);
  const bf16_t* vbase = vt + ((size_t)(bh << 9)) * 1024;
  const float* k2base = k2 + (bh << 10);

  for (int kt = 0; kt < 16; kt++) {
    float k2r[4];
#pragma unroll
    for (int r = 0; r < 4; r++)
      k2r[r] = k2base[kt * 64 + w * 16 + ((l >> 4) << 2) + r];
    f32x4 sacc[4];
#pragma unroll
    for (int it = 0; it < 4; it++) sacc[it] = z4;
#pragma unroll
    for (int kc = 0; kc < 2; kc++) {
      bf16x8 kf = *(const bf16x8*)(kbase + (size_t)(kt * 64 + w * 16 + (l & 15)) * 1024 +
                                   kc * 32 + ((l >> 4) << 3));
#pragma unroll
      for (int it = 0; it < 4; it++)
        sacc[it] = __builtin_amdgcn_mfma_f32_16x16x32_bf16(kf, qf[it][kc], sacc[it], 0, 0, 0);
    }
    __syncthreads();  // previous PV reads of s_lds are done
#pragma unroll
    for (int it = 0; it < 4; it++) {
      int i = it * 16 + (l & 15);
      bf16x4 pk;
#pragma unroll
      for (int r = 0; r < 4; r++) {
        float d2 = fmaxf(q2r[it] + k2r[r] - 2.f * sacc[it][r], 0.f);
        pk[r] = (bf16_t)__expf(d2 * minus_inv);
      }
      int jc8 = (w << 2) + (l >> 4);
      *(bf16x4*)((char*)s_lds + i * 128 + ((jc8 ^ ((i & 7) << 1)) << 3)) = pk;
    }
    __syncthreads();
#pragma unroll
    for (int kc = 0; kc < 2; kc++) {
      bf16x8 sf[4];
#pragma unroll
      for (int m = 0; m < 4; m++) {
        int i = m * 16 + (l & 15);
        int jcA = (kc << 3) + ((l >> 4) << 1);
        sf[m] = *(const bf16x8*)((const char*)s_lds + i * 128 +
                                 ((jcA ^ ((i & 7) << 1)) << 3));
      }
#pragma unroll
      for (int nn = 0; nn < 8; nn++) {
        bf16x8 vf = *(const bf16x8*)(vbase + (size_t)(w * 128 + nn * 16 + (l & 15)) * 1024 +
                                     kt * 64 + (kc << 5) + ((l >> 4) << 3));
#pragma unroll
        for (int m = 0; m < 4; m++)
          acc[m][nn] = __builtin_amdgcn_mfma_f32_16x16x32_bf16(sf[m], vf, acc[m][nn], 0, 0, 0);
      }
    }
  }
#pragma unroll
  for (int m = 0; m < 4; m++) {
    int nidx = (mtile << 6) + m * 16 + ((l >> 4) << 2);
#pragma unroll
    for (int nn = 0; nn < 8; nn++) {
      int col = (h << 9) + w * 128 + nn * 16 + (l & 15);
      bf16_t* o = attn_out + ((size_t)((b << 10) + nidx)) * 4096 + col;
#pragma unroll
      for (int r = 0; r < 4; r++) o[(size_t)r * 4096] = (bf16_t)acc[m][nn][r];
    }
  }
}

// ---------------------------------------------------------------------------
extern "C" void kernel_launch(void* const* d_in, const int* in_sizes, int n_in,
                              void* d_out, int out_size, void* d_ws, size_t ws_size,
                              hipStream_t stream) {
  const float* x    = (const float*)d_in[0];
  const float* pos  = (const float*)d_in[1];
  const float* g1   = (const float*)d_in[2];
  const float* be1  = (const float*)d_in[3];
  const float* scl  = (const float*)d_in[4];
  const float* Wqkv = (const float*)d_in[5];
  const float* bqkv = (const float*)d_in[6];
  const float* Wmrg = (const float*)d_in[7];
  const float* bmrg = (const float*)d_in[8];
  const float* g2   = (const float*)d_in[9];
  const float* be2  = (const float*)d_in[10];
  const float* W1   = (const float*)d_in[11];
  const float* b1   = (const float*)d_in[12];
  const float* g3   = (const float*)d_in[13];
  const float* be3  = (const float*)d_in[14];
  const float* W2   = (const float*)d_in[15];
  const float* b2   = (const float*)d_in[16];
  float* outp = (float*)d_out;

  char* ws = (char*)d_ws;
  size_t off = 0;
  auto alloc = [&](size_t bytes) {
    char* p = ws + off;
    off += (bytes + 255) & ~(size_t)255;
    return p;
  };
  bf16_t* wtq = (bf16_t*)alloc(5120ull * 512 * 2);   // W_qkv^T  (N x K)
  bf16_t* wtm = (bf16_t*)alloc(512ull * 4096 * 2);   // W_merge^T
  bf16_t* wt1 = (bf16_t*)alloc(2048ull * 512 * 2);   // W1^T
  bf16_t* wt2 = (bf16_t*)alloc(512ull * 2048 * 2);   // W2^T
  float*  q2  = (float*)alloc(65536ull * 4);
  float*  k2  = (float*)alloc(65536ull * 4);
  bf16_t* swh = (bf16_t*)alloc(8192ull * 512 * 2);   // swish(norm1(x)+pos)
  bf16_t* qkb = (bf16_t*)alloc(8192ull * 1024 * 2);  // q|k (B,N,1024)
  float*  x2b = (float*)alloc(8192ull * 512 * 4);    // x2 f32
  bf16_t* x2n = (bf16_t*)alloc(8192ull * 512 * 2);   // norm2(x2) bf16
  bf16_t* atn = (bf16_t*)alloc(8192ull * 4096 * 2);  // attention out (B,N,4096)
  bf16_t* vtb = (bf16_t*)alloc(64ull * 512 * 1024 * 2);  // V^T (B,H,512,1024)
  float*  ffh = (float*)vtb;   // alias: FF1 out f32 (8192x2048x4 = same 64MB)
  bf16_t* ffn = (bf16_t*)atn;  // alias: swish(norm3(ffh)) bf16

  dim3 tb(32, 8);
  transp_kernel<<<dim3(512 / 32, 5120 / 32), tb, 0, stream>>>(Wqkv, wtq, 512, 5120);
  transp_kernel<<<dim3(4096 / 32, 512 / 32), tb, 0, stream>>>(Wmrg, wtm, 4096, 512);
  transp_kernel<<<dim3(512 / 32, 2048 / 32), tb, 0, stream>>>(W1, wt1, 512, 2048);
  transp_kernel<<<dim3(2048 / 32, 512 / 32), tb, 0, stream>>>(W2, wt2, 2048, 512);

  norm_kernel<1><<<32, 256, 0, stream>>>(x, g1, be1, pos, swh, 512);
  gemm_bf16<EPI_QKV><<<64 * 40, 256, 0, stream>>>(swh, wtq, bqkv, nullptr,
                                                  (void*)qkb, vtb, 8192, 5120, 512);
  q2k2_kernel<<<256, 256, 0, stream>>>(qkb, q2, k2);
  attn_kernel<<<1024, 256, 0, stream>>>(qkb, vtb, q2, k2, scl, atn);
  gemm_bf16<EPI_F32RES><<<64 * 4, 256, 0, stream>>>(atn, wtm, bmrg, x,
                                                    (void*)x2b, nullptr, 8192, 512, 4096);
  norm_kernel<2><<<32, 256, 0, stream>>>(x2b, g2, be2, nullptr, x2n, 512);
  gemm_bf16<EPI_F32><<<64 * 16, 256, 0, stream>>>(x2n, wt1, b1, nullptr,
                                                  (void*)ffh, nullptr, 8192, 2048, 512);
  norm_kernel<3><<<128, 256, 0, stream>>>(ffh, g3, be3, nullptr, ffn, 2048);
  gemm_bf16<EPI_F32RES><<<64 * 4, 256, 0, stream>>>(ffn, wt2, b2, x2b,
                                                    (void*)outp, nullptr, 8192, 512, 2048);
}

// Round 2
// 544.848 us; speedup vs baseline: 2.4757x; 2.4757x over previous
//
#include <hip/hip_runtime.h>
#include <hip/hip_bf16.h>
#include <stdint.h>

typedef __bf16 bf16_t;
typedef __bf16 bf16x8 __attribute__((ext_vector_type(8)));
typedef __bf16 bf16x4 __attribute__((ext_vector_type(4)));
typedef float f32x4 __attribute__((ext_vector_type(4)));

// ---------------------------------------------------------------------------
// transpose-convert: out[n][k] = (bf16) in[k][n];  in is K x N f32 row-major
// ---------------------------------------------------------------------------
__global__ void transp_kernel(const float* __restrict__ in, bf16_t* __restrict__ out,
                              int K, int N) {
  __shared__ float tile[32][33];
  int k0 = blockIdx.x * 32, n0 = blockIdx.y * 32;
  int tx = threadIdx.x, ty = threadIdx.y;
#pragma unroll
  for (int i = 0; i < 4; i++)
    tile[ty + 8 * i][tx] = in[(size_t)(k0 + ty + 8 * i) * N + n0 + tx];
  __syncthreads();
#pragma unroll
  for (int i = 0; i < 4; i++)
    out[(size_t)(n0 + ty + 8 * i) * K + k0 + tx] = (bf16_t)tile[tx][ty + 8 * i];
}

// ---------------------------------------------------------------------------
// FeatureNorm (stats over sequence dim) -- 3-stage parallel version.
// Stage A: per (b, 128-col chunk, N/S-row chunk) partial sum/sumsq.
// Stage B: reduce S partials -> (mean, rinv) per column.
// Stage C: elementwise apply (+pos/swish variants), float4-vectorized.
// ---------------------------------------------------------------------------
#define NSPLIT 16

__global__ __launch_bounds__(256) void norm_partial(
    const float* __restrict__ in, float* __restrict__ part, int D) {
  const int nd = D >> 7;
  const int bid = blockIdx.x;
  const int s = bid % NSPLIT;
  const int rem = bid / NSPLIT;
  const int dc = rem % nd;
  const int b = rem / nd;
  const int t = threadIdx.x;
  const int d = (dc << 7) + (t & 127);
  const int half = t >> 7;
  const int rows = 1024 / NSPLIT;  // 64
  const float* base = in + ((size_t)b * 1024 + s * rows) * D + d;
  float sum = 0.f, sq = 0.f;
  for (int n = half; n < rows; n += 2) {
    float v = base[(size_t)n * D];
    sum += v;
    sq += v * v;
  }
  __shared__ float r0[256], r1[256];
  r0[t] = sum;
  r1[t] = sq;
  __syncthreads();
  if (t < 128) {
    float ssum = r0[t] + r0[t + 128];
    float ssq = r1[t] + r1[t + 128];
    size_t col = (size_t)b * D + (dc << 7) + t;
    part[col * (2 * NSPLIT) + s] = ssum;
    part[col * (2 * NSPLIT) + NSPLIT + s] = ssq;
  }
}

__global__ __launch_bounds__(256) void norm_stats(
    const float* __restrict__ part, float2* __restrict__ stats, int total) {
  int col = blockIdx.x * 256 + threadIdx.x;
  if (col >= total) return;
  const float* p = part + (size_t)col * (2 * NSPLIT);
  float sum = 0.f, sq = 0.f;
#pragma unroll
  for (int s = 0; s < NSPLIT; s++) {
    sum += p[s];
    sq += p[NSPLIT + s];
  }
  float mean = sum * (1.f / 1024.f);
  float var = sq * (1.f / 1024.f) - mean * mean;
  stats[col] = make_float2(mean, rsqrtf(var + 1e-5f));
}

// MODE 1: +pos then swish.  MODE 2: plain.  MODE 3: swish.
template <int MODE>
__global__ __launch_bounds__(256) void norm_apply(
    const float* __restrict__ in, const float2* __restrict__ stats,
    const float* __restrict__ gamma, const float* __restrict__ beta,
    const float* __restrict__ pos, bf16_t* __restrict__ out, int logD) {
  const int D = 1 << logD;
  size_t idx = ((size_t)blockIdx.x * 256 + threadIdx.x) * 4;
  int d = (int)(idx & (D - 1));
  size_t row = idx >> logD;  // b*1024 + n
  int b = (int)(row >> 10);
  int n = (int)(row & 1023);
  float4 v = *(const float4*)(in + idx);
  float4 g = *(const float4*)(gamma + d);
  float4 be = *(const float4*)(beta + d);
  const float2* st = stats + (size_t)b * D + d;
  float vv[4] = {v.x, v.y, v.z, v.w};
  float gg[4] = {g.x, g.y, g.z, g.w};
  float bb[4] = {be.x, be.y, be.z, be.w};
  float pp[4] = {0.f, 0.f, 0.f, 0.f};
  if (MODE == 1) {
    float4 p = *(const float4*)(pos + (size_t)n * D + d);
    pp[0] = p.x; pp[1] = p.y; pp[2] = p.z; pp[3] = p.w;
  }
  bf16x4 o;
#pragma unroll
  for (int j = 0; j < 4; j++) {
    float2 s = st[j];
    float h = gg[j] * (vv[j] - s.x) * s.y + bb[j];
    if (MODE == 1) h += pp[j];
    if (MODE == 1 || MODE == 3) h = h / (1.f + __expf(-h));
    o[j] = (bf16_t)h;
  }
  *(bf16x4*)(out + idx) = o;
}

// ---------------------------------------------------------------------------
// bf16 GEMM, m97-style: 128x128 tile, BK=64, 4 waves (each 64x64),
// global_load_lds width=16, XOR-swizzled LDS ((row&7) on 16B chunks).
// A: M x K row-major bf16.  Bt: N x K row-major bf16 (i.e. B transposed).
// EPI_QKV : out bf16; cols<1024 -> qk buffer as-is (+bias);
//           cols>=1024 -> V written TRANSPOSED into (B,H,512,1024) (+bias).
// EPI_F32 : out f32 = acc + bias.
// EPI_F32RES: out f32 = acc + bias + res.
// ---------------------------------------------------------------------------
enum { EPI_QKV = 0, EPI_F32 = 1, EPI_F32RES = 2 };

template <int EPI>
__global__ void __launch_bounds__(256, 2) gemm_bf16(
    const bf16_t* __restrict__ A, const bf16_t* __restrict__ Bt,
    const float* __restrict__ bias, const float* __restrict__ res,
    void* __restrict__ out0, bf16_t* __restrict__ out1,
    int M, int N, int K) {
  __shared__ bf16_t smem[2 * 128 * 64];
  bf16_t* sA = smem;
  bf16_t* sB = smem + 128 * 64;
  const int mt = M >> 7;
  const int bm = blockIdx.x % mt;
  const int bn = blockIdx.x / mt;
  const int t = threadIdx.x;
  const int w = t >> 6, l = t & 63;
  const int wm = w >> 1, wn = w & 1;
  const int lrow = l >> 3;
  const int lcol = (l & 7) ^ lrow;  // pre-swizzled global 16B-chunk index

  f32x4 acc[4][4];
  const f32x4 z4 = {0.f, 0.f, 0.f, 0.f};
#pragma unroll
  for (int m = 0; m < 4; m++)
#pragma unroll
    for (int n = 0; n < 4; n++) acc[m][n] = z4;

  const bf16_t* Asrc = A + (size_t)(bm * 128 + w * 32 + lrow) * K + lcol * 8;
  const bf16_t* Bsrc = Bt + (size_t)(bn * 128 + w * 32 + lrow) * K + lcol * 8;

  for (int kk = 0; kk < K; kk += 64) {
#pragma unroll
    for (int i = 0; i < 4; i++) {
      __builtin_amdgcn_global_load_lds(
          (const __attribute__((address_space(1))) void*)(const void*)(Asrc + (size_t)i * 8 * K + kk),
          (__attribute__((address_space(3))) void*)(void*)((char*)sA + (w * 4 + i) * 1024),
          16, 0, 0);
      __builtin_amdgcn_global_load_lds(
          (const __attribute__((address_space(1))) void*)(const void*)(Bsrc + (size_t)i * 8 * K + kk),
          (__attribute__((address_space(3))) void*)(void*)((char*)sB + (w * 4 + i) * 1024),
          16, 0, 0);
    }
    __syncthreads();
#pragma unroll
    for (int ks = 0; ks < 2; ks++) {
      bf16x8 af[4], bfr[4];
      const int lc = ks * 4 + (l >> 4);
#pragma unroll
      for (int m = 0; m < 4; m++) {
        int row = wm * 64 + m * 16 + (l & 15);
        af[m] = *(const bf16x8*)((const char*)sA + row * 128 + ((lc ^ (row & 7)) << 4));
      }
#pragma unroll
      for (int n = 0; n < 4; n++) {
        int row = wn * 64 + n * 16 + (l & 15);
        bfr[n] = *(const bf16x8*)((const char*)sB + row * 128 + ((lc ^ (row & 7)) << 4));
      }
#pragma unroll
      for (int m = 0; m < 4; m++)
#pragma unroll
        for (int n = 0; n < 4; n++)
          acc[m][n] = __builtin_amdgcn_mfma_f32_16x16x32_bf16(af[m], bfr[n], acc[m][n], 0, 0, 0);
    }
    __syncthreads();
  }

  const int rowbase = bm * 128 + wm * 64 + ((l >> 4) << 2);
  const int colbase = bn * 128 + wn * 64 + (l & 15);
#pragma unroll
  for (int m = 0; m < 4; m++) {
#pragma unroll
    for (int n = 0; n < 4; n++) {
      int row = rowbase + m * 16;
      int col = colbase + n * 16;
      float bc = bias[col];
      if (EPI == EPI_QKV) {
        if (col < 1024) {
          bf16_t* qkb = (bf16_t*)out0;
#pragma unroll
          for (int r = 0; r < 4; r++)
            qkb[(size_t)(row + r) * 1024 + col] = (bf16_t)(acc[m][n][r] + bc);
        } else {
          int c2 = col - 1024;
          int hh = c2 >> 9, vc = c2 & 511;
          int bidx = row >> 10, nidx = row & 1023;
          bf16x4 pk;
#pragma unroll
          for (int r = 0; r < 4; r++) pk[r] = (bf16_t)(acc[m][n][r] + bc);
          *(bf16x4*)(out1 + ((size_t)((bidx << 3) + hh) * 512 + vc) * 1024 + nidx) = pk;
        }
      } else {
        float* o = (float*)out0;
#pragma unroll
        for (int r = 0; r < 4; r++) {
          float v = acc[m][n][r] + bc;
          if (EPI == EPI_F32RES) v += res[(size_t)(row + r) * N + col];
          o[(size_t)(row + r) * N + col] = v;
        }
      }
    }
  }
}

// ---------------------------------------------------------------------------
// per-(b,h,n) |q|^2 and |k|^2 over the 64-dim head (from bf16 q/k, f32 accum)
// ---------------------------------------------------------------------------
__global__ void q2k2_kernel(const bf16_t* __restrict__ qk, float* __restrict__ q2,
                            float* __restrict__ k2) {
  int tid = blockIdx.x * 256 + threadIdx.x;  // (b*8+h)*1024 + n
  int b = tid >> 13;
  int h = (tid >> 10) & 7;
  int n = tid & 1023;
  const bf16_t* row = qk + (size_t)((b << 10) + n) * 1024 + (h << 6);
  float sq = 0.f, sk = 0.f;
#pragma unroll
  for (int i = 0; i < 8; i++) {
    bf16x8 vq = *(const bf16x8*)(row + i * 8);
    bf16x8 vk = *(const bf16x8*)(row + 512 + i * 8);
#pragma unroll
    for (int j = 0; j < 8; j++) {
      float fq = (float)vq[j];
      sq += fq * fq;
      float fk = (float)vk[j];
      sk += fk * fk;
    }
  }
  q2[tid] = sq;
  k2[tid] = sk;
}

// ---------------------------------------------------------------------------
// RBF attention: per block (b,h, 64 q-rows).  4 waves.
// S^T = mfma(K,Q) so the P write to LDS is 4-contiguous-j b64 stores.
// score = exp(-max(q2+k2-2qk,0)/scale^2); O = score @ V via LDS-S (A-op) and
// global V^T (B-op, contiguous in kv index).  acc 64x512 f32 per block.
// ---------------------------------------------------------------------------
__global__ void __launch_bounds__(256, 2) attn_kernel(
    const bf16_t* __restrict__ qk, const bf16_t* __restrict__ vt,
    const float* __restrict__ q2, const float* __restrict__ k2,
    const float* __restrict__ scale_p, bf16_t* __restrict__ attn_out) {
  __shared__ bf16_t s_lds[64 * 64];
  const int blk = blockIdx.x;
  const int mtile = blk & 15;
  const int bh = blk >> 4;
  const int b = bh >> 3, h = bh & 7;
  const int t = threadIdx.x, w = t >> 6, l = t & 63;
  const float sc = scale_p[0];
  const float minus_inv = -1.f / (sc * sc);

  const bf16_t* qbase = qk + ((size_t)((b << 10) + (mtile << 6))) * 1024 + (h << 6);
  bf16x8 qf[4][2];
#pragma unroll
  for (int it = 0; it < 4; it++)
#pragma unroll
    for (int kc = 0; kc < 2; kc++)
      qf[it][kc] = *(const bf16x8*)(qbase + (size_t)(it * 16 + (l & 15)) * 1024 +
                                    kc * 32 + ((l >> 4) << 3));
  float q2r[4];
  const float* q2base = q2 + (bh << 10) + (mtile << 6);
#pragma unroll
  for (int it = 0; it < 4; it++) q2r[it] = q2base[it * 16 + (l & 15)];

  f32x4 acc[4][8];
  const f32x4 z4 = {0.f, 0.f, 0.f, 0.f};
#pragma unroll
  for (int m = 0; m < 4; m++)
#pragma unroll
    for (int nn = 0; nn < 8; nn++) acc[m][nn] = z4;

  const bf16_t* kbase = qk + ((size_t)(b << 10)) * 1024 + 512 + (h << 6);
  const bf16_t* vbase = vt + ((size_t)(bh << 9)) * 1024;
  const float* k2base = k2 + (bh << 10);

  for (int kt = 0; kt < 16; kt++) {
    float k2r[4];
#pragma unroll
    for (int r = 0; r < 4; r++)
      k2r[r] = k2base[kt * 64 + w * 16 + ((l >> 4) << 2) + r];
    f32x4 sacc[4];
#pragma unroll
    for (int it = 0; it < 4; it++) sacc[it] = z4;
#pragma unroll
    for (int kc = 0; kc < 2; kc++) {
      bf16x8 kf = *(const bf16x8*)(kbase + (size_t)(kt * 64 + w * 16 + (l & 15)) * 1024 +
                                   kc * 32 + ((l >> 4) << 3));
#pragma unroll
      for (int it = 0; it < 4; it++)
        sacc[it] = __builtin_amdgcn_mfma_f32_16x16x32_bf16(kf, qf[it][kc], sacc[it], 0, 0, 0);
    }
    __syncthreads();  // previous PV reads of s_lds are done
#pragma unroll
    for (int it = 0; it < 4; it++) {
      int i = it * 16 + (l & 15);
      bf16x4 pk;
#pragma unroll
      for (int r = 0; r < 4; r++) {
        float d2 = fmaxf(q2r[it] + k2r[r] - 2.f * sacc[it][r], 0.f);
        pk[r] = (bf16_t)__expf(d2 * minus_inv);
      }
      int jc8 = (w << 2) + (l >> 4);
      *(bf16x4*)((char*)s_lds + i * 128 + ((jc8 ^ ((i & 7) << 1)) << 3)) = pk;
    }
    __syncthreads();
#pragma unroll
    for (int kc = 0; kc < 2; kc++) {
      bf16x8 sf[4];
#pragma unroll
      for (int m = 0; m < 4; m++) {
        int i = m * 16 + (l & 15);
        int jcA = (kc << 3) + ((l >> 4) << 1);
        sf[m] = *(const bf16x8*)((const char*)s_lds + i * 128 +
                                 ((jcA ^ ((i & 7) << 1)) << 3));
      }
#pragma unroll
      for (int nn = 0; nn < 8; nn++) {
        bf16x8 vf = *(const bf16x8*)(vbase + (size_t)(w * 128 + nn * 16 + (l & 15)) * 1024 +
                                     kt * 64 + (kc << 5) + ((l >> 4) << 3));
#pragma unroll
        for (int m = 0; m < 4; m++)
          acc[m][nn] = __builtin_amdgcn_mfma_f32_16x16x32_bf16(sf[m], vf, acc[m][nn], 0, 0, 0);
      }
    }
  }
#pragma unroll
  for (int m = 0; m < 4; m++) {
    int nidx = (mtile << 6) + m * 16 + ((l >> 4) << 2);
#pragma unroll
    for (int nn = 0; nn < 8; nn++) {
      int col = (h << 9) + w * 128 + nn * 16 + (l & 15);
      bf16_t* o = attn_out + ((size_t)((b << 10) + nidx)) * 4096 + col;
#pragma unroll
      for (int r = 0; r < 4; r++) o[(size_t)r * 4096] = (bf16_t)acc[m][nn][r];
    }
  }
}

// ---------------------------------------------------------------------------
extern "C" void kernel_launch(void* const* d_in, const int* in_sizes, int n_in,
                              void* d_out, int out_size, void* d_ws, size_t ws_size,
                              hipStream_t stream) {
  const float* x    = (const float*)d_in[0];
  const float* pos  = (const float*)d_in[1];
  const float* g1   = (const float*)d_in[2];
  const float* be1  = (const float*)d_in[3];
  const float* scl  = (const float*)d_in[4];
  const float* Wqkv = (const float*)d_in[5];
  const float* bqkv = (const float*)d_in[6];
  const float* Wmrg = (const float*)d_in[7];
  const float* bmrg = (const float*)d_in[8];
  const float* g2   = (const float*)d_in[9];
  const float* be2  = (const float*)d_in[10];
  const float* W1   = (const float*)d_in[11];
  const float* b1   = (const float*)d_in[12];
  const float* g3   = (const float*)d_in[13];
  const float* be3  = (const float*)d_in[14];
  const float* W2   = (const float*)d_in[15];
  const float* b2   = (const float*)d_in[16];
  float* outp = (float*)d_out;

  char* ws = (char*)d_ws;
  size_t off = 0;
  auto alloc = [&](size_t bytes) {
    char* p = ws + off;
    off += (bytes + 255) & ~(size_t)255;
    return p;
  };
  bf16_t* wtq = (bf16_t*)alloc(5120ull * 512 * 2);   // W_qkv^T  (N x K)
  bf16_t* wtm = (bf16_t*)alloc(512ull * 4096 * 2);   // W_merge^T
  bf16_t* wt1 = (bf16_t*)alloc(2048ull * 512 * 2);   // W1^T
  bf16_t* wt2 = (bf16_t*)alloc(512ull * 2048 * 2);   // W2^T
  float*  q2  = (float*)alloc(65536ull * 4);
  float*  k2  = (float*)alloc(65536ull * 4);
  float*  prt = (float*)alloc(16384ull * 2 * NSPLIT * 4);  // norm partials
  float2* sts = (float2*)alloc(16384ull * 8);              // norm stats
  bf16_t* swh = (bf16_t*)alloc(8192ull * 512 * 2);   // swish(norm1(x)+pos)
  bf16_t* qkb = (bf16_t*)alloc(8192ull * 1024 * 2);  // q|k (B,N,1024)
  float*  x2b = (float*)alloc(8192ull * 512 * 4);    // x2 f32
  bf16_t* x2n = (bf16_t*)alloc(8192ull * 512 * 2);   // norm2(x2) bf16
  bf16_t* atn = (bf16_t*)alloc(8192ull * 4096 * 2);  // attention out (B,N,4096)
  bf16_t* vtb = (bf16_t*)alloc(64ull * 512 * 1024 * 2);  // V^T (B,H,512,1024)
  float*  ffh = (float*)vtb;   // alias: FF1 out f32 (8192x2048x4 = same 64MB)
  bf16_t* ffn = (bf16_t*)atn;  // alias: swish(norm3(ffh)) bf16

  dim3 tb(32, 8);
  transp_kernel<<<dim3(512 / 32, 5120 / 32), tb, 0, stream>>>(Wqkv, wtq, 512, 5120);
  transp_kernel<<<dim3(4096 / 32, 512 / 32), tb, 0, stream>>>(Wmrg, wtm, 4096, 512);
  transp_kernel<<<dim3(512 / 32, 2048 / 32), tb, 0, stream>>>(W1, wt1, 512, 2048);
  transp_kernel<<<dim3(2048 / 32, 512 / 32), tb, 0, stream>>>(W2, wt2, 2048, 512);

  // ---- norm1 (+pos, swish) -> swh (bf16) ----
  norm_partial<<<8 * 4 * NSPLIT, 256, 0, stream>>>(x, prt, 512);
  norm_stats<<<16, 256, 0, stream>>>(prt, sts, 8 * 512);
  norm_apply<1><<<4096, 256, 0, stream>>>(x, sts, g1, be1, pos, swh, 9);

  gemm_bf16<EPI_QKV><<<64 * 40, 256, 0, stream>>>(swh, wtq, bqkv, nullptr,
                                                  (void*)qkb, vtb, 8192, 5120, 512);
  q2k2_kernel<<<256, 256, 0, stream>>>(qkb, q2, k2);
  attn_kernel<<<1024, 256, 0, stream>>>(qkb, vtb, q2, k2, scl, atn);
  gemm_bf16<EPI_F32RES><<<64 * 4, 256, 0, stream>>>(atn, wtm, bmrg, x,
                                                    (void*)x2b, nullptr, 8192, 512, 4096);

  // ---- norm2 (plain) -> x2n (bf16) ----
  norm_partial<<<8 * 4 * NSPLIT, 256, 0, stream>>>(x2b, prt, 512);
  norm_stats<<<16, 256, 0, stream>>>(prt, sts, 8 * 512);
  norm_apply<2><<<4096, 256, 0, stream>>>(x2b, sts, g2, be2, nullptr, x2n, 9);

  gemm_bf16<EPI_F32><<<64 * 16, 256, 0, stream>>>(x2n, wt1, b1, nullptr,
                                                  (void*)ffh, nullptr, 8192, 2048, 512);

  // ---- norm3 (swish) -> ffn (bf16) ----
  norm_partial<<<8 * 16 * NSPLIT, 256, 0, stream>>>(ffh, prt, 2048);
  norm_stats<<<64, 256, 0, stream>>>(prt, sts, 8 * 2048);
  norm_apply<3><<<16384, 256, 0, stream>>>(ffh, sts, g3, be3, nullptr, ffn, 11);

  gemm_bf16<EPI_F32RES><<<64 * 4, 256, 0, stream>>>(ffn, wt2, b2, x2b,
                                                    (void*)outp, nullptr, 8192, 512, 2048);
}